// Round 16
// baseline (151.316 us; speedup 1.0000x reference)
//
#include <hip/hip_runtime.h>
#include <hip/hip_bf16.h>

// Fused Interaction Estimator, v16: v12 + wave-private W streaming via DMA.
// 6144 blocks x 256 threads, 16-row tile. B (W) fragments no longer loaded
// global->reg inside the gemm (8 serial ~250cy L2 windows/gemm); instead each
// wave DMAs its own 4KB W chunk (64 cols x 32 k) into a wave-private
// double-buffered LDS region, issuing chunk t+2 right after consuming chunk t
// (counted vmcnt(4), no barriers added -- wave-private). The g-gemm tail
// prefetches the p-gemm's first two chunks; B2's existing vmcnt(0) covers
// them. In-order vmcnt retirement keeps counts correct under arbitrary
// compiler-placed param loads (needed chunk is always older than the <=4
// newest ops). LDS 17.4->50 KB (3 blocks/CU, down from 4 -- accepted).

typedef float f32x4 __attribute__((ext_vector_type(4)));
typedef short short8 __attribute__((ext_vector_type(8)));
typedef unsigned int u32;

#define D_DIM 256
#define ROWS 16
#define NW 4

union S8 { short8 s; u32 u[4]; };

__device__ __forceinline__ u32 f2bfu(float x) {   // RNE f32->bf16 (finite)
  u32 u = __float_as_uint(x);
  return (u + 0x7FFFu + ((u >> 16) & 1u)) >> 16;
}
__device__ __forceinline__ float sigm(float x) { return 1.0f / (1.0f + __expf(-x)); }

__device__ __forceinline__ u32 pk2c(float a, float b) {   // -> v_cvt_pk_bf16_f32
  __hip_bfloat162 h = __float22bfloat162_rn(float2{a, b});
  union { __hip_bfloat162 h; u32 u; } cv;
  cv.h = h;
  return cv.u;
}

#define WAITV(n) asm volatile("s_waitcnt vmcnt(" #n ")" ::: "memory")
#define WAITL    asm volatile("s_waitcnt lgkmcnt(0)" ::: "memory")

// ---------------- prep: pack W (f32 [k][m] row-major) into bf16 MFMA B-fragment order ----
// chunk = c*512 + t*64 + l holds 8 bf16: B[k = t*32 + (l>>4)*8 + j][m = c*16 + (l&15)]
__global__ __launch_bounds__(256) void pack_w_kernel(const float* __restrict__ Wg,
                                                     const float* __restrict__ Wp,
                                                     unsigned short* __restrict__ outp) {
  int b = blockIdx.x;
  const float* W = (b < 32) ? Wg : Wp;
  unsigned short* o = outp + (b < 32 ? 0 : 65536);
  int chunk = (b & 31) * 256 + threadIdx.x;
  int c = chunk >> 9;
  int rest = chunk & 511;
  int t = rest >> 6;
  int l = rest & 63;
  int m = c * 16 + (l & 15);
  int kb = t * 32 + ((l >> 4) << 3);
  short8 v;
#pragma unroll
  for (int j = 0; j < 8; ++j) v[j] = (short)f2bfu(W[(kb + j) * 256 + m]);
  *(short8*)(o + (size_t)chunk * 8) = v;
}

// ---------------- main fused kernel ----------------

// A tile: 4 row-DMAs per wave (f32, source-swizzled at 16B granules)
__device__ __forceinline__ void stage_dma(const float* __restrict__ src, float* lbuf,
                                          int w, int lane) {
#pragma unroll
  for (int j = 0; j < 4; ++j) {
    int r = w * 4 + j;
    const float* gp = src + r * D_DIM + ((lane ^ (r & 7)) << 2);
    float* lp = lbuf + r * D_DIM;
    __builtin_amdgcn_global_load_lds(
        (const __attribute__((address_space(1))) u32*)gp,
        (__attribute__((address_space(3))) u32*)lp, 16, 0, 0);
  }
}

// W chunk DMA: wave w's 4KB slice of K-step t (4 fragments = 4 x 1KB)
__device__ __forceinline__ void w_dma(const unsigned short* __restrict__ wsrc,
                                      unsigned short* wdst, int w, int t, int lane) {
#pragma unroll
  for (int j = 0; j < 4; ++j) {
    const unsigned short* gp = wsrc + (((w * 4 + j) * 512 + t * 64 + lane) << 3);
    unsigned short* lp = wdst + j * 512;   // wave-uniform; HW adds lane*16
    __builtin_amdgcn_global_load_lds(
        (const __attribute__((address_space(1))) u32*)gp,
        (__attribute__((address_space(3))) u32*)lp, 16, 0, 0);
  }
}

__device__ __forceinline__ void barrier_fence() {
  __builtin_amdgcn_s_barrier();
  asm volatile("" ::: "memory");
}

// read A-fragment (t) from swizzled f32 LDS tile and convert to bf16
__device__ __forceinline__ short8 readAf32(const float* buf, int t, int lane) {
  const int cl = lane & 15, kg = lane >> 4;
  const int r = cl;
  const int s = r & 7;
  const int c16 = t * 8 + kg * 2;
  const char* base = (const char*)buf + r * 1024;
  float4 x = *(const float4*)(base + ((c16 ^ s) << 4));
  float4 y = *(const float4*)(base + (((c16 + 1) ^ s) << 4));
  S8 rr;
  rr.u[0] = pk2c(x.x, x.y);
  rr.u[1] = pk2c(x.z, x.w);
  rr.u[2] = pk2c(y.x, y.y);
  rr.u[3] = pk2c(y.z, y.w);
  return rr.s;
}

// bias + per-row (sum, sumsq) partials
__device__ __forceinline__ void statsPhase(f32x4 acc[4], const float bv[4],
                                           float smS[NW][ROWS], float smQ[NW][ROWS],
                                           int lane, int w) {
#pragma unroll
  for (int r = 0; r < 4; ++r) {
    float s = 0.f, qq = 0.f;
#pragma unroll
    for (int c = 0; c < 4; ++c) {
      float y = acc[c][r] + bv[c];
      acc[c][r] = y;
      s += y; qq += y * y;
    }
#pragma unroll
    for (int m = 1; m < 16; m <<= 1) {
      s += __shfl_xor(s, m, 64);
      qq += __shfl_xor(qq, m, 64);
    }
    if ((lane & 15) == 0) {
      int row = ((lane >> 4) << 2) + r;
      smS[w][row] = s;
      smQ[w][row] = qq;
    }
  }
}

__device__ __forceinline__ void applyPhase(f32x4 acc[4], f32x4 outAl[4],
                                           const float gv[4], const float tv[4], const float wv[4],
                                           const float smS[NW][ROWS], const float smQ[NW][ROWS],
                                           float smRed[NW][ROWS], int lane, int w) {
#pragma unroll
  for (int r = 0; r < 4; ++r) {
    int row = ((lane >> 4) << 2) + r;
    float s = 0.f, qq = 0.f;
#pragma unroll
    for (int k = 0; k < NW; ++k) { s += smS[k][row]; qq += smQ[k][row]; }
    float mu = s * (1.0f / 256.0f);
    float var = fmaxf(qq * (1.0f / 256.0f) - mu * mu, 0.0f);
    float rs = rsqrtf(var + 1e-5f);
    float dp = 0.f;
#pragma unroll
    for (int c = 0; c < 4; ++c) {
      float a = (acc[c][r] - mu) * rs * gv[c] + tv[c];
      a = fmaxf(a, 0.0f);
      outAl[c][r] = a;
      dp += a * wv[c];
    }
#pragma unroll
    for (int m = 1; m < 16; m <<= 1) dp += __shfl_xor(dp, m, 64);
    if ((lane & 15) == 0) smRed[w][row] = dp;
  }
}

__global__ __launch_bounds__(256, 4) void fused_main(
    const float* __restrict__ gfeat, const float* __restrict__ pfeat,
    const float* __restrict__ bg, const float* __restrict__ glng, const float* __restrict__ glnb,
    const float* __restrict__ bp, const float* __restrict__ plng, const float* __restrict__ plnb,
    const float* __restrict__ wag, const float* __restrict__ bag,
    const float* __restrict__ wap, const float* __restrict__ bap,
    const unsigned short* __restrict__ wpk,
    float* __restrict__ outp)
{
  __shared__ float bufA[ROWS * D_DIM];              // 16 KB f32 A (g then p)
  __shared__ unsigned short smW[NW][2][2048];       // 32 KB: per-wave W dbuf (2 x 4KB)
  __shared__ float smS[NW][ROWS], smQ[NW][ROWS], smRG[NW][ROWS], smRP[NW][ROWS];

  const int tid = threadIdx.x;
  const int lane = tid & 63;
  const int w = tid >> 6;
  const size_t row0 = (size_t)blockIdx.x * ROWS;

  const unsigned short* wgS = wpk;            // packed Wg base (shorts)
  const unsigned short* wpS = wpk + 65536;    // packed Wp base

  // prologue DMAs: A-g (4), Wg chunk0 (4), Wg chunk1 (4)
  stage_dma(gfeat + row0 * D_DIM, bufA, w, lane);
  w_dma(wgS, &smW[w][0][0], w, 0, lane);
  w_dma(wgS, &smW[w][1][0], w, 1, lane);

  // params (compiler places; extra loads can't break counted waits: in-order
  // retirement means the needed chunk is always older than the <=4 newest)
  const int cb = w * 64 + (lane & 15);
  float bvG[4], bvP[4];
#pragma unroll
  for (int c = 0; c < 4; ++c) {
    bvG[c] = bg[cb + c * 16];
    bvP[c] = bp[cb + c * 16];
  }
  const float vbag = bag[0], vbap = bap[0];

  WAITV(8);                              // A-g done (c0/c1 may still fly)
  barrier_fence();                       // B0: A-g staged block-wide

  f32x4 accG[4];
#pragma unroll
  for (int c = 0; c < 4; ++c) accG[c] = {0.f, 0.f, 0.f, 0.f};

  // ---- g gemm: consume chunk t (buf t&1), then refill same buf with t+2 ----
#pragma unroll
  for (int t = 0; t < 8; ++t) {
    WAITV(4);                            // chunk t done (only chunk t+1 newer)
    short8 a = readAf32(bufA, t, lane);
    const unsigned short* wl = &smW[w][t & 1][0];
#pragma unroll
    for (int c = 0; c < 4; ++c) {
      short8 b = *(const short8*)(wl + c * 512 + lane * 8);
      accG[c] = __builtin_amdgcn_mfma_f32_16x16x32_bf16(a, b, accG[c], 0, 0, 0);
    }
    __builtin_amdgcn_sched_barrier(0);   // pin: reads/MFMAs retire before refill issue
    if (t < 6) w_dma(wgS, &smW[w][t & 1][0], w, t + 2, lane);
    else       w_dma(wpS, &smW[w][t & 1][0], w, t - 6, lane);   // prefetch Wp c0/c1
  }

  statsPhase(accG, bvG, smS, smQ, lane, w);
  WAITL;
  barrier_fence();                       // B1: statsG visible; g-reads of bufA done

  stage_dma(pfeat + row0 * D_DIM, bufA, w, lane);   // A-p into same buffer

  float gvG[4], tvG[4], wvG[4], gvP[4], tvP[4], wvP[4];
#pragma unroll
  for (int c = 0; c < 4; ++c) {
    gvG[c] = glng[cb + c * 16];
    tvG[c] = glnb[cb + c * 16];
    wvG[c] = wap[cb + c * 16];
    gvP[c] = plng[cb + c * 16];
    tvP[c] = plnb[cb + c * 16];
    wvP[c] = wag[cb + c * 16];
  }

  f32x4 alignG[4];
  applyPhase(accG, alignG, gvG, tvG, wvG, smS, smQ, smRG, lane, w);
  WAITV(0);                              // A-p + Wp c0/c1 done (issued earlier)
  WAITL;
  barrier_fence();                       // B2: p staged; smRG visible; smS reads done

  f32x4 accP[4];
#pragma unroll
  for (int c = 0; c < 4; ++c) accP[c] = {0.f, 0.f, 0.f, 0.f};

  // ---- p gemm ----
#pragma unroll
  for (int t = 0; t < 8; ++t) {
    if (t >= 1 && t <= 6) { WAITV(4); }
    else if (t == 7)      { WAITV(0); }
    // t==0: drained at B2
    short8 a = readAf32(bufA, t, lane);
    const unsigned short* wl = &smW[w][t & 1][0];
#pragma unroll
    for (int c = 0; c < 4; ++c) {
      short8 b = *(const short8*)(wl + c * 512 + lane * 8);
      accP[c] = __builtin_amdgcn_mfma_f32_16x16x32_bf16(a, b, accP[c], 0, 0, 0);
    }
    __builtin_amdgcn_sched_barrier(0);
    if (t < 6) w_dma(wpS, &smW[w][t & 1][0], w, t + 2, lane);
  }

  statsPhase(accP, bvP, smS, smQ, lane, w);   // smS rewrite: applyG reads ended at B2
  WAITL;
  barrier_fence();                       // B3: statsP visible

  applyPhase(accP, accP, gvP, tvP, wvP, smS, smQ, smRP, lane, w);  // acc := alignP
  WAITL;
  barrier_fence();                       // B4: smRP visible

  // fusion + store
#pragma unroll
  for (int r = 0; r < 4; ++r) {
    int row = ((lane >> 4) << 2) + r;
    float gr = 0.f, pr = 0.f;
#pragma unroll
    for (int k = 0; k < NW; ++k) { gr += smRG[k][row]; pr += smRP[k][row]; }
    float* orow = outp + (row0 + row) * D_DIM + w * 64 + (lane & 15);
#pragma unroll
    for (int c = 0; c < 4; ++c) {
      float ga = alignG[c][r];
      float pa = accP[c][r];
      float geno = sigm(ga * pr + vbag);
      float path = sigm(pa * gr + vbap);
      orow[c * 16] = pa * path + ga * geno;
    }
  }
}

extern "C" void kernel_launch(void* const* d_in, const int* in_sizes, int n_in,
                              void* d_out, int out_size, void* d_ws, size_t ws_size,
                              hipStream_t stream) {
  const float* gfeat = (const float*)d_in[0];
  const float* pfeat = (const float*)d_in[1];
  const float* Wg   = (const float*)d_in[2];
  const float* bg   = (const float*)d_in[3];
  const float* glng = (const float*)d_in[4];
  const float* glnb = (const float*)d_in[5];
  const float* Wp   = (const float*)d_in[6];
  const float* bp   = (const float*)d_in[7];
  const float* plng = (const float*)d_in[8];
  const float* plnb = (const float*)d_in[9];
  const float* wag  = (const float*)d_in[10];
  const float* bag  = (const float*)d_in[11];
  const float* wap  = (const float*)d_in[12];
  const float* bap  = (const float*)d_in[13];
  float* outp = (float*)d_out;
  unsigned short* wpk = (unsigned short*)d_ws;   // 256 KB used

  hipLaunchKernelGGL(pack_w_kernel, dim3(64), dim3(256), 0, stream, Wg, Wp, wpk);

  int nrows = in_sizes[0] / D_DIM;   // 98304
  int nblocks = nrows / ROWS;        // 6144
  hipLaunchKernelGGL(fused_main, dim3(nblocks), dim3(256), 0, stream,
                     gfeat, pfeat, bg, glng, glnb, bp, plng, plnb,
                     wag, bag, wap, bap, wpk, outp);
}

// Round 17
// 144.727 us; speedup vs baseline: 1.0455x; 1.0455x over previous
//
#include <hip/hip_runtime.h>
#include <hip/hip_bf16.h>

// Fused Interaction Estimator, v17: 512-thread merged blocks, bf16-A staging.
// 3072 blocks x 512 threads (8 waves), one 32-row tile per block.
// - ONE exposed HBM window per block: all 8 A-float4 loads (g+p) issue at
//   entry (64KB/block in flight), reg-staged, converted to bf16 and written
//   to LDS in v1's proven XOR-swizzled layout. bf16 A => 1 ds_read_b128 per
//   fragment and ZERO in-gemm cvt_pk (VALU cut ~20%).
// - Merged 3-barrier schedule (v15): gemm-g + gemm-p -> stats both -> B1 ->
//   apply both -> B2 -> fuse. 3 barriers per 32 rows vs v12's 10.
// - Register budget audited <= 60 at every phase; __launch_bounds__(512,4)
//   caps at 64 (the empirically-best tier: ~16 waves/CU).

typedef float f32x4 __attribute__((ext_vector_type(4)));
typedef short short8 __attribute__((ext_vector_type(8)));
typedef unsigned int u32;

#define D_DIM 256
#define ROWS 32
#define NWV 8

union S8 { short8 s; u32 u[4]; };

__device__ __forceinline__ u32 f2bfu(float x) {   // RNE f32->bf16 (finite)
  u32 u = __float_as_uint(x);
  return (u + 0x7FFFu + ((u >> 16) & 1u)) >> 16;
}
__device__ __forceinline__ float sigm(float x) { return 1.0f / (1.0f + __expf(-x)); }

__device__ __forceinline__ u32 pk2c(float a, float b) {   // -> v_cvt_pk_bf16_f32
  __hip_bfloat162 h = __float22bfloat162_rn(float2{a, b});
  union { __hip_bfloat162 h; u32 u; } cv;
  cv.h = h;
  return cv.u;
}

#define WAITL asm volatile("s_waitcnt lgkmcnt(0)" ::: "memory")

// ---------------- prep: pack W (f32 [k][m] row-major) into bf16 MFMA B-fragment order ----
// chunk = c*512 + t*64 + l holds 8 bf16: B[k = t*32 + (l>>4)*8 + j][m = c*16 + (l&15)]
__global__ __launch_bounds__(256) void pack_w_kernel(const float* __restrict__ Wg,
                                                     const float* __restrict__ Wp,
                                                     unsigned short* __restrict__ outp) {
  int b = blockIdx.x;
  const float* W = (b < 32) ? Wg : Wp;
  unsigned short* o = outp + (b < 32 ? 0 : 65536);
  int chunk = (b & 31) * 256 + threadIdx.x;
  int c = chunk >> 9;
  int rest = chunk & 511;
  int t = rest >> 6;
  int l = rest & 63;
  int m = c * 16 + (l & 15);
  int kb = t * 32 + ((l >> 4) << 3);
  short8 v;
#pragma unroll
  for (int j = 0; j < 8; ++j) v[j] = (short)f2bfu(W[(kb + j) * 256 + m]);
  *(short8*)(o + (size_t)chunk * 8) = v;
}

// ---------------- main fused kernel ----------------

__device__ __forceinline__ void barrier_fence() {
  __builtin_amdgcn_s_barrier();
  asm volatile("" ::: "memory");
}

// convert 4 float4 (16 f32) to bf16 and write XOR-swizzled (v1-proven layout)
__device__ __forceinline__ void stageWrite(const float4 v[4], unsigned short* smA, int tid) {
#pragma unroll
  for (int it = 0; it < 4; ++it) {
    int idx = it * 512 + tid;          // float4 index, 2048 per 32x256 tile
    int row = idx >> 6;                // 64 float4 per row
    int k4 = (idx & 63) << 2;          // f32 index within row
    uint2 hv;
    hv.x = pk2c(v[it].x, v[it].y);
    hv.y = pk2c(v[it].z, v[it].w);
    int off = (row * 512 + k4 * 2) ^ ((row & 7) << 4);
    *(uint2*)((char*)smA + off) = hv;
  }
}

// read bf16 A-fragment (rt, t): one ds_read_b128, no conversion
__device__ __forceinline__ short8 readA(const unsigned short* smA, int rt, int t, int lane) {
  int row = rt * 16 + (lane & 15);
  int off = (row * 512 + t * 64 + ((lane >> 4) << 4)) ^ ((row & 7) << 4);
  return *(const short8*)((const char*)smA + off);
}

// bias + per-row (sum, sumsq) partials; wave w covers cols w*32..w*32+31
__device__ __forceinline__ void statsPhase(f32x4 acc[2][2], const float bv[2],
                                           float smS[NWV][ROWS], float smQ[NWV][ROWS],
                                           int lane, int w) {
  const int cl = lane & 15, kg = lane >> 4;
#pragma unroll
  for (int rt = 0; rt < 2; ++rt) {
#pragma unroll
    for (int r = 0; r < 4; ++r) {
      float s = 0.f, qq = 0.f;
#pragma unroll
      for (int cc = 0; cc < 2; ++cc) {
        float y = acc[rt][cc][r] + bv[cc];
        acc[rt][cc][r] = y;
        s += y; qq += y * y;
      }
#pragma unroll
      for (int m = 1; m < 16; m <<= 1) {
        s += __shfl_xor(s, m, 64);
        qq += __shfl_xor(qq, m, 64);
      }
      if (cl == 0) {
        int row = rt * 16 + kg * 4 + r;
        smS[w][row] = s;
        smQ[w][row] = qq;
      }
    }
  }
}

__device__ __forceinline__ void applyPhase(f32x4 acc[2][2],
                                           const float gv[2], const float tv[2], const float wv[2],
                                           const float smS[NWV][ROWS], const float smQ[NWV][ROWS],
                                           float smRed[NWV][ROWS], int lane, int w) {
  const int cl = lane & 15, kg = lane >> 4;
#pragma unroll
  for (int rt = 0; rt < 2; ++rt) {
#pragma unroll
    for (int r = 0; r < 4; ++r) {
      int row = rt * 16 + kg * 4 + r;
      float s = 0.f, qq = 0.f;
#pragma unroll
      for (int k = 0; k < NWV; ++k) { s += smS[k][row]; qq += smQ[k][row]; }
      float mu = s * (1.0f / 256.0f);
      float var = fmaxf(qq * (1.0f / 256.0f) - mu * mu, 0.0f);
      float rs = rsqrtf(var + 1e-5f);
      float dp = 0.f;
#pragma unroll
      for (int cc = 0; cc < 2; ++cc) {
        float a = (acc[rt][cc][r] - mu) * rs * gv[cc] + tv[cc];
        a = fmaxf(a, 0.0f);
        acc[rt][cc][r] = a;      // in place: acc becomes align
        dp += a * wv[cc];
      }
#pragma unroll
      for (int m = 1; m < 16; m <<= 1) dp += __shfl_xor(dp, m, 64);
      if (cl == 0) smRed[w][row] = dp;
    }
  }
}

__global__ __launch_bounds__(512, 4) void fused_main(
    const float* __restrict__ gfeat, const float* __restrict__ pfeat,
    const float* __restrict__ bg, const float* __restrict__ glng, const float* __restrict__ glnb,
    const float* __restrict__ bp, const float* __restrict__ plng, const float* __restrict__ plnb,
    const float* __restrict__ wag, const float* __restrict__ bag,
    const float* __restrict__ wap, const float* __restrict__ bap,
    const unsigned short* __restrict__ wpk,
    float* __restrict__ outp)
{
  __shared__ unsigned short bufG[ROWS * D_DIM];   // 16 KB bf16, XOR-swizzled
  __shared__ unsigned short bufP[ROWS * D_DIM];   // 16 KB
  __shared__ float smSG[NWV][ROWS], smQG[NWV][ROWS];
  __shared__ float smSP[NWV][ROWS], smQP[NWV][ROWS];
  __shared__ float smRG[NWV][ROWS], smRP[NWV][ROWS];

  const int tid = threadIdx.x;
  const int lane = tid & 63;
  const int w = tid >> 6;
  const int cl = lane & 15, kg = lane >> 4;
  const size_t row0 = (size_t)blockIdx.x * ROWS;

  // ---- staging: issue ALL 8 A-loads (g+p) at entry -> one HBM window ----
  const float4* g4 = (const float4*)(gfeat + row0 * D_DIM);
  const float4* p4 = (const float4*)(pfeat + row0 * D_DIM);
  float4 vg[4], vp[4];
#pragma unroll
  for (int it = 0; it < 4; ++it) vg[it] = g4[it * 512 + tid];
#pragma unroll
  for (int it = 0; it < 4; ++it) vp[it] = p4[it * 512 + tid];
  const float vbag = bag[0], vbap = bap[0];

  stageWrite(vg, bufG, tid);       // compiler inserts the single vmcnt wait
  stageWrite(vp, bufP, tid);
  WAITL;
  barrier_fence();                 // B0: both bf16 tiles staged

  // biases load here: L2 latency covered by gemm-g
  const int cb = w * 32 + cl;
  float bvG[2], bvP[2];
#pragma unroll
  for (int cc = 0; cc < 2; ++cc) {
    bvG[cc] = bg[cb + cc * 16];
    bvP[cc] = bp[cb + cc * 16];
  }

  // ---- merged gemms: wave w owns cols w*32..+31 (c = w*2 + cc) ----
  const short8* wbg = (const short8*)wpk;
  const short8* wbp = (const short8*)(wpk + 65536);
  const int bbase = w * 1024 + lane;     // (w*2)*512 + lane

  f32x4 accG[2][2], accP[2][2];
#pragma unroll
  for (int rt = 0; rt < 2; ++rt)
#pragma unroll
    for (int cc = 0; cc < 2; ++cc) {
      accG[rt][cc] = {0.f, 0.f, 0.f, 0.f};
      accP[rt][cc] = {0.f, 0.f, 0.f, 0.f};
    }

#pragma unroll
  for (int t = 0; t < 8; ++t) {
    short8 x0 = readA(bufG, 0, t, lane);
    short8 x1 = readA(bufG, 1, t, lane);
    short8 b0 = wbg[bbase + t * 64];
    short8 b1 = wbg[bbase + 512 + t * 64];
    accG[0][0] = __builtin_amdgcn_mfma_f32_16x16x32_bf16(x0, b0, accG[0][0], 0, 0, 0);
    accG[1][0] = __builtin_amdgcn_mfma_f32_16x16x32_bf16(x1, b0, accG[1][0], 0, 0, 0);
    accG[0][1] = __builtin_amdgcn_mfma_f32_16x16x32_bf16(x0, b1, accG[0][1], 0, 0, 0);
    accG[1][1] = __builtin_amdgcn_mfma_f32_16x16x32_bf16(x1, b1, accG[1][1], 0, 0, 0);
  }
#pragma unroll
  for (int t = 0; t < 8; ++t) {
    short8 x0 = readA(bufP, 0, t, lane);
    short8 x1 = readA(bufP, 1, t, lane);
    short8 b0 = wbp[bbase + t * 64];
    short8 b1 = wbp[bbase + 512 + t * 64];
    accP[0][0] = __builtin_amdgcn_mfma_f32_16x16x32_bf16(x0, b0, accP[0][0], 0, 0, 0);
    accP[1][0] = __builtin_amdgcn_mfma_f32_16x16x32_bf16(x1, b0, accP[1][0], 0, 0, 0);
    accP[0][1] = __builtin_amdgcn_mfma_f32_16x16x32_bf16(x0, b1, accP[0][1], 0, 0, 0);
    accP[1][1] = __builtin_amdgcn_mfma_f32_16x16x32_bf16(x1, b1, accP[1][1], 0, 0, 0);
  }

  // ---- stats both; LN params load under their cover ----
  statsPhase(accG, bvG, smSG, smQG, lane, w);
  statsPhase(accP, bvP, smSP, smQP, lane, w);

  float gvG[2], tvG[2], wvG[2], gvP[2], tvP[2], wvP[2];
#pragma unroll
  for (int cc = 0; cc < 2; ++cc) {
    gvG[cc] = glng[cb + cc * 16];
    tvG[cc] = glnb[cb + cc * 16];
    wvG[cc] = wap[cb + cc * 16];   // g_align . wa_p
    gvP[cc] = plng[cb + cc * 16];
    tvP[cc] = plnb[cb + cc * 16];
    wvP[cc] = wag[cb + cc * 16];   // p_align . wa_g
  }
  WAITL;
  barrier_fence();                 // B1: all stats partials visible

  applyPhase(accG, gvG, tvG, wvG, smSG, smQG, smRG, lane, w);   // accG := alignG
  applyPhase(accP, gvP, tvP, wvP, smSP, smQP, smRP, lane, w);   // accP := alignP
  WAITL;
  barrier_fence();                 // B2: smRG/smRP visible

  // ---- fusion + store ----
#pragma unroll
  for (int rt = 0; rt < 2; ++rt) {
#pragma unroll
    for (int r = 0; r < 4; ++r) {
      int row = rt * 16 + kg * 4 + r;
      float gr = 0.f, pr = 0.f;
#pragma unroll
      for (int k = 0; k < NWV; ++k) { gr += smRG[k][row]; pr += smRP[k][row]; }
      float* orow = outp + (row0 + row) * D_DIM + w * 32 + cl;
#pragma unroll
      for (int cc = 0; cc < 2; ++cc) {
        float ga = accG[rt][cc][r];
        float pa = accP[rt][cc][r];
        float geno = sigm(ga * pr + vbag);
        float path = sigm(pa * gr + vbap);
        orow[cc * 16] = pa * path + ga * geno;
      }
    }
  }
}

extern "C" void kernel_launch(void* const* d_in, const int* in_sizes, int n_in,
                              void* d_out, int out_size, void* d_ws, size_t ws_size,
                              hipStream_t stream) {
  const float* gfeat = (const float*)d_in[0];
  const float* pfeat = (const float*)d_in[1];
  const float* Wg   = (const float*)d_in[2];
  const float* bg   = (const float*)d_in[3];
  const float* glng = (const float*)d_in[4];
  const float* glnb = (const float*)d_in[5];
  const float* Wp   = (const float*)d_in[6];
  const float* bp   = (const float*)d_in[7];
  const float* plng = (const float*)d_in[8];
  const float* plnb = (const float*)d_in[9];
  const float* wag  = (const float*)d_in[10];
  const float* bag  = (const float*)d_in[11];
  const float* wap  = (const float*)d_in[12];
  const float* bap  = (const float*)d_in[13];
  float* outp = (float*)d_out;
  unsigned short* wpk = (unsigned short*)d_ws;   // 256 KB used

  hipLaunchKernelGGL(pack_w_kernel, dim3(64), dim3(256), 0, stream, Wg, Wp, wpk);

  int nrows = in_sizes[0] / D_DIM;   // 98304
  int nblocks = nrows / ROWS;        // 3072
  hipLaunchKernelGGL(fused_main, dim3(nblocks), dim3(512), 0, stream,
                     gfeat, pfeat, bg, glng, glnb, bp, plng, plnb,
                     wag, bag, wap, bap, wpk, outp);
}